// Round 5
// baseline (310.201 us; speedup 1.0000x reference)
//
#include <hip/hip_runtime.h>
#include <hip/hip_bf16.h>
#include <math.h>

#define HDIM 100
#define NFACT 262144
#define NBLK  1024            // NFACT / 256

using short8 = __attribute__((ext_vector_type(8))) short;
using f32x4  = __attribute__((ext_vector_type(4))) float;

// ---------------- ws float-offset layout ----------------
#define WS_B     0                    // 14336 floats = 7*8*64 uint4 B-fragments (bf16 bits)
#define WS_SP    14336                // NBLK partial softmax denoms
#define WS_PC    (WS_SP + NBLK)       // NBLK*100 partial weighted sums [block][h]
// end = 15360 + 102400 = 117760 floats (~460 KB)

__device__ __forceinline__ unsigned short f2bf(float x) {
    unsigned u = __builtin_bit_cast(unsigned, x);
    u += 0x7FFFu + ((u >> 16) & 1u);          // RNE round to bf16
    return (unsigned short)(u >> 16);
}

__device__ __forceinline__ float tanh_fast(float x) {
    float e = __expf(2.0f * x);
    return 1.0f - 2.0f / (1.0f + e);
}

// ---- Precompute W1 as MFMA B-fragments (bf16), frag order [jt][kc][lane][8] ----
// B[k][j]: j = jt*16 + (lane&15); k = kc*32 + (lane>>4)*8 + e.
// k in [0,128): half A (f - oc), valid if (k&127) < 100; k in [128,256): half B (f - m).
__global__ __launch_bounds__(256) void k_prep_b(const float* __restrict__ W1,
                                                float* __restrict__ ws) {
    int t = blockIdx.x * 256 + threadIdx.x;   // 0..3583
    if (t >= 7 * 8 * 64) return;
    int lane = t & 63;
    int kc = (t >> 6) & 7;
    int jt = t >> 9;
    int g = lane >> 4, r = lane & 15;
    int j = jt * 16 + r;
    unsigned short v[8];
    #pragma unroll
    for (int e = 0; e < 8; e++) {
        int kglob = kc * 32 + g * 8 + e;
        int half = kglob >> 7;
        int koff = kglob & 127;
        float x = 0.f;
        if (j < HDIM && koff < HDIM) x = W1[j * 200 + half * HDIM + koff];
        v[e] = f2bf(x);
    }
    uint4 d;
    d.x = (unsigned)v[0] | ((unsigned)v[1] << 16);
    d.y = (unsigned)v[2] | ((unsigned)v[3] << 16);
    d.z = (unsigned)v[4] | ((unsigned)v[5] << 16);
    d.w = (unsigned)v[6] | ((unsigned)v[7] << 16);
    ((uint4*)(ws + WS_B))[t] = d;
}

__device__ __forceinline__ float4 ld4c(const float* p, bool ok) {
    float4 z = make_float4(0.f, 0.f, 0.f, 0.f);
    return ok ? *(const float4*)p : z;
}

__device__ __forceinline__ short8 absdiff_bf16(float4 a0, float4 a1,
                                               float4 b0, float4 b1) {
    union { __hip_bfloat16 h[8]; short8 v; } u;
    u.h[0] = __float2bfloat16(fabsf(a0.x - b0.x));
    u.h[1] = __float2bfloat16(fabsf(a0.y - b0.y));
    u.h[2] = __float2bfloat16(fabsf(a0.z - b0.z));
    u.h[3] = __float2bfloat16(fabsf(a0.w - b0.w));
    u.h[4] = __float2bfloat16(fabsf(a1.x - b1.x));
    u.h[5] = __float2bfloat16(fabsf(a1.y - b1.y));
    u.h[6] = __float2bfloat16(fabsf(a1.z - b1.z));
    u.h[7] = __float2bfloat16(fabsf(a1.w - b1.w));
    return u.v;
}

// Fused: logits (MFMA) + softmax partials + weighted pooling, fe read EXACTLY once.
// 512 threads (8 waves), 256 facts/block. Raw f kept in registers for pooling.
__global__ __launch_bounds__(512, 4) void k_logits(
        const float* __restrict__ fe,
        const float* __restrict__ oc,
        const float* __restrict__ mvec,
        const float* __restrict__ b1,
        const float* __restrict__ W2,
        float* __restrict__ ws) {
    __shared__ uint4 Bs[3584];           // 57344 B
    __shared__ float gv[256];
    __shared__ float wls[256];
    __shared__ float sred[8];
    __shared__ float poolbuf[8 * 128];   // per-wave column partials

    int t = threadIdx.x;
    int w = t >> 6, lane = t & 63, g = lane >> 4, r = lane & 15;
    int n0 = blockIdx.x * 256;

    // stage B fragments (57344 B) from ws (L2-resident)
    {
        const uint4* src = (const uint4*)(ws + WS_B);
        #pragma unroll
        for (int i = 0; i < 7; i++) Bs[t + i * 512] = src[t + i * 512];
    }

    // Load this lane's two fact rows ONCE into registers (cols c*32+g*8 .. +8).
    float4 f0a[4], f0b[4], f1a[4], f1b[4];
    {
        const float* fp0 = fe + (long)(n0 + w * 32 + r) * HDIM;
        const float* fp1 = fe + (long)(n0 + w * 32 + 16 + r) * HDIM;
        #pragma unroll
        for (int c = 0; c < 4; c++) {
            int base = c * 32 + g * 8;
            bool v0 = base < HDIM, v1 = base + 4 < HDIM;
            f0a[c] = ld4c(fp0 + base, v0); f0b[c] = ld4c(fp0 + base + 4, v1);
            f1a[c] = ld4c(fp1 + base, v0); f1b[c] = ld4c(fp1 + base + 4, v1);
        }
    }
    __syncthreads();

    // Tile-sequential GEMM (keeps VGPR under the 4-wave cap).
    #pragma unroll
    for (int tile = 0; tile < 2; tile++) {
        short8 afrag[8];
        #pragma unroll
        for (int c = 0; c < 4; c++) {
            int base = c * 32 + g * 8;
            bool v0 = base < HDIM, v1 = base + 4 < HDIM;
            float4 oa = ld4c(oc + base, v0),   ob = ld4c(oc + base + 4, v1);
            float4 ma = ld4c(mvec + base, v0), mb = ld4c(mvec + base + 4, v1);
            float4 fa = tile ? f1a[c] : f0a[c];
            float4 fb = tile ? f1b[c] : f0b[c];
            afrag[c]     = absdiff_bf16(fa, fb, oa, ob);   // |f - oc| half
            afrag[4 + c] = absdiff_bf16(fa, fb, ma, mb);   // |f - m| half
        }
        float gpart[4] = {0, 0, 0, 0};
        #pragma unroll
        for (int jt = 0; jt < 7; jt++) {
            f32x4 acc = {0, 0, 0, 0};
            #pragma unroll
            for (int kc = 0; kc < 8; kc++) {
                short8 bv = __builtin_bit_cast(short8, Bs[(jt * 8 + kc) * 64 + lane]);
                acc = __builtin_amdgcn_mfma_f32_16x16x32_bf16(afrag[kc], bv, acc, 0, 0, 0);
            }
            int j = jt * 16 + r;
            float w2j = (j < HDIM) ? W2[j] : 0.f;
            float b1j = (j < HDIM) ? b1[j] : 0.f;
            #pragma unroll
            for (int q = 0; q < 4; q++)
                gpart[q] = fmaf(tanh_fast(acc[q] + b1j), w2j, gpart[q]);
        }
        // reduce over j (r lanes); C row = fact = g*4+q
        #pragma unroll
        for (int q = 0; q < 4; q++) {
            float v = gpart[q];
            v += __shfl_xor(v, 1); v += __shfl_xor(v, 2);
            v += __shfl_xor(v, 4); v += __shfl_xor(v, 8);
            if (r == 0) gv[w * 32 + tile * 16 + g * 4 + q] = v;
        }
    }
    __syncthreads();

    // weights = exp(logit) directly: |logit| <= sum|W2| ~ 8, no max-shift needed.
    float e = 0.f;
    if (t < 256) {
        e = __expf(gv[t]);
        wls[t] = e;
    }
    float s = e;
    #pragma unroll
    for (int off = 32; off; off >>= 1) s += __shfl_down(s, off);
    if (lane == 0 && t < 256) sred[w] = s;
    __syncthreads();
    if (t == 0) ws[WS_SP + blockIdx.x] = ((sred[0] + sred[1]) + (sred[2] + sred[3]));

    // pooling from registers: p = w0*f0 + w1*f1, reduce across the 16 r-lanes.
    float w0 = wls[w * 32 + r];
    float w1 = wls[w * 32 + 16 + r];
    float4 pa[4], pb[4];
    #pragma unroll
    for (int c = 0; c < 4; c++) {
        pa[c].x = fmaf(w0, f0a[c].x, w1 * f1a[c].x);
        pa[c].y = fmaf(w0, f0a[c].y, w1 * f1a[c].y);
        pa[c].z = fmaf(w0, f0a[c].z, w1 * f1a[c].z);
        pa[c].w = fmaf(w0, f0a[c].w, w1 * f1a[c].w);
        pb[c].x = fmaf(w0, f0b[c].x, w1 * f1b[c].x);
        pb[c].y = fmaf(w0, f0b[c].y, w1 * f1b[c].y);
        pb[c].z = fmaf(w0, f0b[c].z, w1 * f1b[c].z);
        pb[c].w = fmaf(w0, f0b[c].w, w1 * f1b[c].w);
    }
    #pragma unroll
    for (int mask = 1; mask <= 8; mask <<= 1) {
        #pragma unroll
        for (int c = 0; c < 4; c++) {
            pa[c].x += __shfl_xor(pa[c].x, mask);
            pa[c].y += __shfl_xor(pa[c].y, mask);
            pa[c].z += __shfl_xor(pa[c].z, mask);
            pa[c].w += __shfl_xor(pa[c].w, mask);
            pb[c].x += __shfl_xor(pb[c].x, mask);
            pb[c].y += __shfl_xor(pb[c].y, mask);
            pb[c].z += __shfl_xor(pb[c].z, mask);
            pb[c].w += __shfl_xor(pb[c].w, mask);
        }
    }
    if (r == 0) {
        #pragma unroll
        for (int c = 0; c < 4; c++) {
            int base = c * 32 + g * 8;
            *(float4*)(poolbuf + w * 128 + base)     = pa[c];
            *(float4*)(poolbuf + w * 128 + base + 4) = pb[c];
        }
    }
    __syncthreads();
    if (t < HDIM) {
        float c = 0.f;
        #pragma unroll
        for (int ww = 0; ww < 8; ww++) c += poolbuf[ww * 128 + t];
        ws[WS_PC + (long)blockIdx.x * HDIM + t] = c;
    }
}

// Combine per-block partials, normalize, gated update. One block.
__global__ __launch_bounds__(1024) void k_final(
        const float* __restrict__ mvec,
        const float* __restrict__ oc,
        const float* __restrict__ W3,
        const float* __restrict__ b3,
        const float* __restrict__ ws,
        float* __restrict__ out) {
    __shared__ float sred[16];
    __shared__ float csl[1000];
    __shared__ float vv[300];
    __shared__ float Sval;
    int t = threadIdx.x;
    int w = t >> 6, lane = t & 63;

    // S = sum of 1024 partial denoms
    float s = ws[WS_SP + t];
    #pragma unroll
    for (int off = 32; off; off >>= 1) s += __shfl_down(s, off);
    if (lane == 0) sred[w] = s;

    // c[h] partials over block-slices (1000 threads)
    if (t < 1000) {
        int sl = t / 100, h = t % 100;
        float a = 0.f;
        #pragma unroll 4
        for (int b = sl; b < NBLK; b += 10) a += ws[WS_PC + (long)b * HDIM + h];
        csl[t] = a;
    }
    __syncthreads();
    if (t == 0) {
        float a = 0.f;
        #pragma unroll
        for (int i = 0; i < 16; i++) a += sred[i];
        Sval = a;
    }
    __syncthreads();
    if (t < HDIM) {
        float c = 0.f;
        #pragma unroll
        for (int sl = 0; sl < 10; sl++) c += csl[sl * 100 + t];
        vv[t] = mvec[t];
        vv[HDIM + t] = c / Sval;
        vv[2 * HDIM + t] = oc[t];
    }
    __syncthreads();
    if (t < HDIM) {
        float a = b3[t];
        const float* wr = W3 + t * 3 * HDIM;
        #pragma unroll 4
        for (int k = 0; k < 3 * HDIM; k++) a = fmaf(wr[k], vv[k], a);
        out[t] = fmaxf(a, 0.f);
    }
}

extern "C" void kernel_launch(void* const* d_in, const int* in_sizes, int n_in,
                              void* d_out, int out_size, void* d_ws, size_t ws_size,
                              hipStream_t stream) {
    const float* mvec = (const float*)d_in[0];
    const float* oh   = (const float*)d_in[1];
    const float* fe   = (const float*)d_in[2];
    const float* W1   = (const float*)d_in[3];
    const float* b1   = (const float*)d_in[4];
    const float* W2   = (const float*)d_in[5];
    const float* W3   = (const float*)d_in[7];
    const float* b3   = (const float*)d_in[8];
    float* ws  = (float*)d_ws;
    float* out = (float*)d_out;

    k_prep_b<<<14, 256, 0, stream>>>(W1, ws);
    k_logits<<<NBLK, 512, 0, stream>>>(fe, oh, mvec, b1, W2, ws);
    k_final<<<1, 1024, 0, stream>>>(mvec, oh, W3, b3, ws, out);
}

// Round 6
// 97.397 us; speedup vs baseline: 3.1849x; 3.1849x over previous
//
#include <hip/hip_runtime.h>
#include <hip/hip_bf16.h>
#include <math.h>

#define HDIM 100
#define NFACT 262144
#define NBLK  1024            // NFACT / 256

using short8 = __attribute__((ext_vector_type(8))) short;
using f32x4  = __attribute__((ext_vector_type(4))) float;

// K packed to 208: k in [0,104) -> |f - oc| half (valid k<100), k in [104,208) -> |f - m| half.
// 7 kc tiles of 32 cover 224; kglob in [208,224) is dead (B zero there).
#define KDIM 208
#define NJT  7                // j tiles (112 >= 100)
#define NKC  7                // k tiles of 32 (224 >= 208)
#define NBFRAG (NJT * NKC * 64)   // 3136 uint4

// ---------------- ws float-offset layout ----------------
#define WS_B     0                    // 3136*4 = 12544 floats (B fragments, bf16 bits)
#define WS_SP    12544                // NBLK partial softmax denoms
#define WS_PC    (WS_SP + NBLK)       // NBLK*100 partial weighted sums [block][h]

__device__ __forceinline__ unsigned short f2bf(float x) {
    unsigned u = __builtin_bit_cast(unsigned, x);
    u += 0x7FFFu + ((u >> 16) & 1u);          // RNE round to bf16
    return (unsigned short)(u >> 16);
}

__device__ __forceinline__ float tanh_fast(float x) {
    float e = __expf(2.0f * x);
    return 1.0f - 2.0f / (1.0f + e);
}

// ---- Precompute W1 as MFMA B-fragments (bf16), frag order [jt][kc][lane][8] ----
// B[k][j]: j = jt*16 + (lane&15); k = kc*32 + (lane>>4)*8 + e.
__global__ __launch_bounds__(256) void k_prep_b(const float* __restrict__ W1,
                                                float* __restrict__ ws) {
    int t = blockIdx.x * 256 + threadIdx.x;
    if (t >= NBFRAG) return;
    int lane = t & 63;
    int kc = (t >> 6) % NKC;
    int jt = t / (NKC * 64);
    int g = lane >> 4, r = lane & 15;
    int j = jt * 16 + r;
    unsigned short v[8];
    #pragma unroll
    for (int e = 0; e < 8; e++) {
        int kglob = kc * 32 + g * 8 + e;
        int half = (kglob >= 104) ? 1 : 0;
        int koff = kglob - half * 104;
        float x = 0.f;
        if (kglob < KDIM && j < HDIM && koff < HDIM)
            x = W1[j * 200 + half * HDIM + koff];
        v[e] = f2bf(x);
    }
    uint4 d;
    d.x = (unsigned)v[0] | ((unsigned)v[1] << 16);
    d.y = (unsigned)v[2] | ((unsigned)v[3] << 16);
    d.z = (unsigned)v[4] | ((unsigned)v[5] << 16);
    d.w = (unsigned)v[6] | ((unsigned)v[7] << 16);
    ((uint4*)(ws + WS_B))[t] = d;
}

__device__ __forceinline__ short8 absdiff_bf16(float4 a0, float4 a1,
                                               float4 b0, float4 b1) {
    union { unsigned short us[8]; short8 v; } u;
    u.us[0] = f2bf(fabsf(a0.x - b0.x));
    u.us[1] = f2bf(fabsf(a0.y - b0.y));
    u.us[2] = f2bf(fabsf(a0.z - b0.z));
    u.us[3] = f2bf(fabsf(a0.w - b0.w));
    u.us[4] = f2bf(fabsf(a1.x - b1.x));
    u.us[5] = f2bf(fabsf(a1.y - b1.y));
    u.us[6] = f2bf(fabsf(a1.z - b1.z));
    u.us[7] = f2bf(fabsf(a1.w - b1.w));
    return u.v;
}

#define FTS 104                // ftile row stride (floats); 104%32=8 -> 4-way max on frag reads

// Fused: coalesced-stage fe tile to LDS -> MFMA logits -> softmax partials ->
// pooling from the SAME LDS tile. fe read exactly once, fully coalesced.
// 512 threads (8 waves), 256 facts/block, 1 block/CU (LDS-capped).
__global__ __launch_bounds__(512) void k_logits(
        const float* __restrict__ fe,
        const float* __restrict__ oc,
        const float* __restrict__ mvec,
        const float* __restrict__ b1,
        const float* __restrict__ W2,
        float* __restrict__ ws) {
    __shared__ float ftile[256 * FTS];   // 106,496 B
    __shared__ uint4 Bs[NBFRAG];         // 50,176 B
    __shared__ float ocm[224];           // 896 B   (208..223 = 0)
    __shared__ float gv[256];
    __shared__ float wls[256];
    __shared__ float sred[8];
    __shared__ float poolbuf[4][HDIM];

    int t = threadIdx.x;
    int w = t >> 6, lane = t & 63, g = lane >> 4, r = lane & 15;

    // ---- coalesced stage: fe tile (6400 float4) ----
    {
        const float4* fe4 = (const float4*)(fe + (long)blockIdx.x * 256 * HDIM);
        float4 vbuf[12];
        #pragma unroll
        for (int i = 0; i < 12; i++) vbuf[i] = fe4[t + i * 512];
        float4 vt;
        if (t < 256) vt = fe4[6144 + t];
        #pragma unroll
        for (int i = 0; i < 12; i++) {
            int e4 = t + i * 512;
            int row = e4 / 25, c4 = e4 % 25;
            *(float4*)(ftile + row * FTS + c4 * 4) = vbuf[i];
        }
        if (t < 256) {
            int e4 = 6144 + t;
            int row = e4 / 25, c4 = e4 % 25;
            *(float4*)(ftile + row * FTS + c4 * 4) = vt;
        }
        // zero pad cols 100..103
        if (t < 256) *(float4*)(ftile + t * FTS + HDIM) = make_float4(0, 0, 0, 0);
    }
    // ---- stage B fragments from ws (L2/L3-resident) ----
    {
        const uint4* src = (const uint4*)(ws + WS_B);
        uint4 bbuf[6];
        #pragma unroll
        for (int i = 0; i < 6; i++) bbuf[i] = src[t + i * 512];
        uint4 bt;
        if (t < 64) bt = src[3072 + t];
        #pragma unroll
        for (int i = 0; i < 6; i++) Bs[t + i * 512] = bbuf[i];
        if (t < 64) Bs[3072 + t] = bt;
    }
    // ---- stage oc|m combined, zero-padded ----
    if (t < 224) {
        float x = 0.f;
        if (t < 104)            { if (t < HDIM) x = oc[t]; }
        else if (t < KDIM)      { int k = t - 104; if (k < HDIM) x = mvec[k]; }
        ocm[t] = x;
    }
    __syncthreads();

    // ---- build A fragments from LDS ----
    short8 afrag[2][NKC];
    #pragma unroll
    for (int tile = 0; tile < 2; tile++) {
        int row = w * 32 + tile * 16 + r;
        const float* frow = ftile + row * FTS;
        #pragma unroll
        for (int kc = 0; kc < NKC; kc++) {
            int kglob = kc * 32 + g * 8;         // per-lane
            bool dead = kglob >= KDIM;           // B is zero there; just keep values finite
            int half = (kglob >= 104) ? 1 : 0;
            int col = dead ? 0 : (kglob - half * 104);
            int ko  = dead ? KDIM : kglob;       // ocm[208..223]=0
            float4 fa = *(const float4*)(frow + col);
            float4 fb = *(const float4*)(frow + col + 4);
            float4 oa = *(const float4*)(ocm + ko);
            float4 ob = *(const float4*)(ocm + ko + 4);
            afrag[tile][kc] = absdiff_bf16(fa, fb, oa, ob);
        }
    }

    // ---- GEMM + fused epilogue ----
    float gpart[2][4] = {{0, 0, 0, 0}, {0, 0, 0, 0}};
    #pragma unroll
    for (int jt = 0; jt < NJT; jt++) {
        f32x4 acc0 = {0, 0, 0, 0}, acc1 = {0, 0, 0, 0};
        #pragma unroll
        for (int kc = 0; kc < NKC; kc++) {
            short8 bv = __builtin_bit_cast(short8, Bs[(jt * NKC + kc) * 64 + lane]);
            acc0 = __builtin_amdgcn_mfma_f32_16x16x32_bf16(afrag[0][kc], bv, acc0, 0, 0, 0);
            acc1 = __builtin_amdgcn_mfma_f32_16x16x32_bf16(afrag[1][kc], bv, acc1, 0, 0, 0);
        }
        int j = jt * 16 + r;
        float w2j = (j < HDIM) ? W2[j] : 0.f;
        float b1j = (j < HDIM) ? b1[j] : 0.f;
        #pragma unroll
        for (int q = 0; q < 4; q++) {
            gpart[0][q] = fmaf(tanh_fast(acc0[q] + b1j), w2j, gpart[0][q]);
            gpart[1][q] = fmaf(tanh_fast(acc1[q] + b1j), w2j, gpart[1][q]);
        }
    }

    // reduce over j (r lanes); C row = fact = g*4+q within tile
    #pragma unroll
    for (int tile = 0; tile < 2; tile++) {
        #pragma unroll
        for (int q = 0; q < 4; q++) {
            float v = gpart[tile][q];
            v += __shfl_xor(v, 1); v += __shfl_xor(v, 2);
            v += __shfl_xor(v, 4); v += __shfl_xor(v, 8);
            if (r == 0) gv[w * 32 + tile * 16 + g * 4 + q] = v;
        }
    }
    __syncthreads();

    // weights = exp(logit) directly (|logit| <= sum|W2| ~ 8; b2 dropped, softmax-invariant)
    float e = 0.f;
    if (t < 256) {
        e = __expf(gv[t]);
        wls[t] = e;
    }
    float s = e;
    #pragma unroll
    for (int off = 32; off; off >>= 1) s += __shfl_down(s, off);
    if (lane == 0) sred[w] = s;
    __syncthreads();
    if (t == 0) {
        float S_p = 0.f;
        #pragma unroll
        for (int i = 0; i < 8; i++) S_p += sred[i];
        ws[WS_SP + blockIdx.x] = S_p;
    }

    // ---- pooling from the SAME LDS tile ----
    if (t < 400) {
        int quarter = t / HDIM, k = t % HDIM;
        float c = 0.f;
        const float* fp = ftile + quarter * 64 * FTS + k;
        const float* wp = wls + quarter * 64;
        #pragma unroll 4
        for (int n = 0; n < 64; n++) c = fmaf(wp[n], fp[n * FTS], c);
        poolbuf[quarter][k] = c;
    }
    __syncthreads();
    if (t < HDIM) {
        float c = poolbuf[0][t] + poolbuf[1][t] + poolbuf[2][t] + poolbuf[3][t];
        ws[WS_PC + (long)blockIdx.x * HDIM + t] = c;
    }
}

// Combine per-block partials, normalize, gated update. One block.
__global__ __launch_bounds__(1024) void k_final(
        const float* __restrict__ mvec,
        const float* __restrict__ oc,
        const float* __restrict__ W3,
        const float* __restrict__ b3,
        const float* __restrict__ ws,
        float* __restrict__ out) {
    __shared__ float sred[16];
    __shared__ float csl[1000];
    __shared__ float vv[300];
    __shared__ float Sval;
    int t = threadIdx.x;
    int w = t >> 6, lane = t & 63;

    float s = ws[WS_SP + t];
    #pragma unroll
    for (int off = 32; off; off >>= 1) s += __shfl_down(s, off);
    if (lane == 0) sred[w] = s;

    if (t < 1000) {
        int sl = t / 100, h = t % 100;
        float a = 0.f;
        #pragma unroll 4
        for (int b = sl; b < NBLK; b += 10) a += ws[WS_PC + (long)b * HDIM + h];
        csl[t] = a;
    }
    __syncthreads();
    if (t == 0) {
        float a = 0.f;
        #pragma unroll
        for (int i = 0; i < 16; i++) a += sred[i];
        Sval = a;
    }
    __syncthreads();
    if (t < HDIM) {
        float c = 0.f;
        #pragma unroll
        for (int sl = 0; sl < 10; sl++) c += csl[sl * 100 + t];
        vv[t] = mvec[t];
        vv[HDIM + t] = c / Sval;
        vv[2 * HDIM + t] = oc[t];
    }
    __syncthreads();
    if (t < HDIM) {
        float a = b3[t];
        const float* wr = W3 + t * 3 * HDIM;
        #pragma unroll 4
        for (int k = 0; k < 3 * HDIM; k++) a = fmaf(wr[k], vv[k], a);
        out[t] = fmaxf(a, 0.f);
    }
}

extern "C" void kernel_launch(void* const* d_in, const int* in_sizes, int n_in,
                              void* d_out, int out_size, void* d_ws, size_t ws_size,
                              hipStream_t stream) {
    const float* mvec = (const float*)d_in[0];
    const float* oh   = (const float*)d_in[1];
    const float* fe   = (const float*)d_in[2];
    const float* W1   = (const float*)d_in[3];
    const float* b1   = (const float*)d_in[4];
    const float* W2   = (const float*)d_in[5];
    const float* W3   = (const float*)d_in[7];
    const float* b3   = (const float*)d_in[8];
    float* ws  = (float*)d_ws;
    float* out = (float*)d_out;

    k_prep_b<<<13, 256, 0, stream>>>(W1, ws);
    k_logits<<<NBLK, 512, 0, stream>>>(fe, oh, mvec, b1, W2, ws);
    k_final<<<1, 1024, 0, stream>>>(mvec, oh, W3, b3, ws, out);
}